// Round 3
// baseline (68.600 us; speedup 1.0000x reference)
//
#include <hip/hip_runtime.h>
#include <hip/hip_bf16.h>

// One thread per sample. 4-qubit state (16 complex) lives in registers.
// Pre-CNOT circuit collapsed to tensor product of per-wire 2-vectors;
// CNOTs are compile-time index swaps; final Rx layer folded into the
// Z-measurement via Rx' Z Rx = cos(t) Z + sin(t) Y.
// Dtypes: inputs fp32 [n,4], theta fp32 [16], out fp32 [n,4,1].

__global__ __launch_bounds__(256) void qsim_kernel(
        const float* __restrict__ x,      // [n,4] float32
        const float* __restrict__ theta,  // [16]  float32
        float* __restrict__ out,          // [n,4] float32
        int n) {
    // ---- per-block: compose trainable constants into LDS (lanes 0..3) ----
    __shared__ __align__(16) float cst[40];
    int tid = threadIdx.x;
    if (tid < 4) {
        int q = tid;
        float a = theta[3*q], bb = theta[3*q+1], c = theta[3*q+2];
        float sa, ca, sb, cb, sc, cc;
        __sincosf(0.5f*a,  &sa, &ca);
        __sincosf(0.5f*bb, &sb, &cb);
        __sincosf(0.5f*c,  &sc, &cc);
        // M = Ry(bb) * Rx(a)
        float m00r =  cb*ca, m00i =  sb*sa;
        float m01r = -sb*ca, m01i = -cb*sa;
        float m10r =  sb*ca, m10i = -cb*sa;
        float m11r =  cb*ca, m11i = -sb*sa;
        // T = Rz(c) * M : row0 *= (cc - i sc), row1 *= (cc + i sc)
        float* T = cst + 8*q;
        T[0] = cc*m00r + sc*m00i;  T[1] = cc*m00i - sc*m00r;
        T[2] = cc*m01r + sc*m01i;  T[3] = cc*m01i - sc*m01r;
        T[4] = cc*m10r - sc*m10i;  T[5] = cc*m10i + sc*m10r;
        T[6] = cc*m11r - sc*m11i;  T[7] = cc*m11i + sc*m11r;
        // final rx(theta[12+q]) folded into measurement: cos(t), 2*sin(t)
        float sfq, cfq;
        __sincosf(theta[12+q], &sfq, &cfq);
        cst[32+q] = cfq;
        cst[36+q] = 2.0f*sfq;
    }
    __syncthreads();

    int b = blockIdx.x * 256 + tid;
    if (b >= n) return;

    float4 xv = ((const float4*)x)[b];

    // broadcast constants from LDS
    float T[32];
    #pragma unroll
    for (int i = 0; i < 8; ++i) ((float4*)T)[i] = ((const float4*)cst)[i];
    float4 cf  = ((const float4*)cst)[8];
    float4 sf2 = ((const float4*)cst)[9];

    float s0,c0,s1,c1,s2,c2,s3,c3;
    __sincosf(0.5f*xv.x, &s0, &c0);
    __sincosf(0.5f*xv.y, &s1, &c1);
    __sincosf(0.5f*xv.z, &s2, &c2);
    __sincosf(0.5f*xv.w, &s3, &c3);

    // v_q = T_q * (Enc_q |0>), a = component |0>, b = component |1>
    float var[4], vai[4], vbr[4], vbi[4];
    {   // wire0: rx(x0): e = (c0, -i s0)
        const float* t = T + 0;
        var[0] = t[0]*c0 + t[3]*s0;  vai[0] = t[1]*c0 - t[2]*s0;
        vbr[0] = t[4]*c0 + t[7]*s0;  vbi[0] = t[5]*c0 - t[6]*s0;
    }
    {   // wire1: ry(x1): e = (c1, s1)
        const float* t = T + 8;
        var[1] = t[0]*c1 + t[2]*s1;  vai[1] = t[1]*c1 + t[3]*s1;
        vbr[1] = t[4]*c1 + t[6]*s1;  vbi[1] = t[5]*c1 + t[7]*s1;
    }
    {   // wire2: rz(x2): e = (c2 - i s2, 0) -> v = (c2 - i s2) * T[:,0]
        const float* t = T + 16;
        var[2] = t[0]*c2 + t[1]*s2;  vai[2] = t[1]*c2 - t[0]*s2;
        vbr[2] = t[4]*c2 + t[5]*s2;  vbi[2] = t[5]*c2 - t[4]*s2;
    }
    {   // wire3: rx(x3)
        const float* t = T + 24;
        var[3] = t[0]*c3 + t[3]*s3;  vai[3] = t[1]*c3 - t[2]*s3;
        vbr[3] = t[4]*c3 + t[7]*s3;  vbi[3] = t[5]*c3 - t[6]*s3;
    }

    // tensor products: index i = 8*b0 + 4*b1 + 2*b2 + b3 (wire0 = MSB)
    float u01r[4], u01i[4], u23r[4], u23i[4];
    #pragma unroll
    for (int i0 = 0; i0 < 2; ++i0) {
        float ar = i0 ? vbr[0] : var[0], ai = i0 ? vbi[0] : vai[0];
        #pragma unroll
        for (int i1 = 0; i1 < 2; ++i1) {
            float br = i1 ? vbr[1] : var[1], bi = i1 ? vbi[1] : vai[1];
            u01r[2*i0+i1] = ar*br - ai*bi;
            u01i[2*i0+i1] = ar*bi + ai*br;
        }
    }
    #pragma unroll
    for (int i2 = 0; i2 < 2; ++i2) {
        float ar = i2 ? vbr[2] : var[2], ai = i2 ? vbi[2] : vai[2];
        #pragma unroll
        for (int i3 = 0; i3 < 2; ++i3) {
            float br = i3 ? vbr[3] : var[3], bi = i3 ? vbi[3] : vai[3];
            u23r[2*i2+i3] = ar*br - ai*bi;
            u23i[2*i2+i3] = ar*bi + ai*br;
        }
    }
    float pr[16], pi[16];
    #pragma unroll
    for (int h = 0; h < 4; ++h)
        #pragma unroll
        for (int l = 0; l < 4; ++l) {
            pr[4*h+l] = u01r[h]*u23r[l] - u01i[h]*u23i[l];
            pi[4*h+l] = u01r[h]*u23i[l] + u01i[h]*u23r[l];
        }

    // CNOTs (0,1),(1,2),(2,3),(3,0): constant-index swaps (register renames)
    #define SWP(A,Bq) { float t_; t_=pr[A]; pr[A]=pr[Bq]; pr[Bq]=t_; \
                        t_=pi[A]; pi[A]=pi[Bq]; pi[Bq]=t_; }
    SWP(8,12)  SWP(9,13)  SWP(10,14) SWP(11,15)   // CNOT(0,1): c=bit8, t=bit4
    SWP(4,6)   SWP(5,7)   SWP(12,14) SWP(13,15)   // CNOT(1,2): c=bit4, t=bit2
    SWP(2,3)   SWP(6,7)   SWP(10,11) SWP(14,15)   // CNOT(2,3): c=bit2, t=bit1
    SWP(1,9)   SWP(3,11)  SWP(5,13)  SWP(7,15)    // CNOT(3,0): c=bit1, t=bit8
    #undef SWP

    // probabilities
    float d[16];
    #pragma unroll
    for (int i = 0; i < 16; ++i) d[i] = pr[i]*pr[i] + pi[i]*pi[i];

    // <Z_w> via shared tree
    float s1a[8], d1[8];
    #pragma unroll
    for (int k = 0; k < 8; ++k) { s1a[k] = d[2*k]+d[2*k+1]; d1[k] = d[2*k]-d[2*k+1]; }
    float z3 = ((d1[0]+d1[1])+(d1[2]+d1[3])) + ((d1[4]+d1[5])+(d1[6]+d1[7]));
    float s2a[4], d2[4];
    #pragma unroll
    for (int k = 0; k < 4; ++k) { s2a[k] = s1a[2*k]+s1a[2*k+1]; d2[k] = s1a[2*k]-s1a[2*k+1]; }
    float z2 = (d2[0]+d2[1]) + (d2[2]+d2[3]);
    float s3a[2], d3[2];
    #pragma unroll
    for (int k = 0; k < 2; ++k) { s3a[k] = s2a[2*k]+s2a[2*k+1]; d3[k] = s2a[2*k]-s2a[2*k+1]; }
    float z1 = d3[0] + d3[1];
    float z0 = s3a[0] - s3a[1];

    // <Y_w> = 2 * sum_pairs Im(conj(a0)*a1); factor 2 folded into sf2
    float y[4];
    #pragma unroll
    for (int w = 0; w < 4; ++w) {
        int m = 8 >> w;
        float acc = 0.f;
        #pragma unroll
        for (int i = 0; i < 16; ++i)
            if (!(i & m)) acc += pr[i]*pi[i+m] - pi[i]*pr[i+m];
        y[w] = acc;
    }

    float4 o;
    o.x = cf.x*z0 + sf2.x*y[0];
    o.y = cf.y*z1 + sf2.y*y[1];
    o.z = cf.z*z2 + sf2.z*y[2];
    o.w = cf.w*z3 + sf2.w*y[3];
    ((float4*)out)[b] = o;
}

extern "C" void kernel_launch(void* const* d_in, const int* in_sizes, int n_in,
                              void* d_out, int out_size, void* d_ws, size_t ws_size,
                              hipStream_t stream) {
    const float* inputs = (const float*)d_in[0];
    const float* theta  = (const float*)d_in[1];
    float* out = (float*)d_out;
    int n = in_sizes[0] / 4;
    int blocks = (n + 255) / 256;
    qsim_kernel<<<blocks, 256, 0, stream>>>(inputs, theta, out, n);
}

// Round 4
// 67.883 us; speedup vs baseline: 1.0106x; 1.0106x over previous
//
#include <hip/hip_runtime.h>
#include <hip/hip_bf16.h>

// One thread per sample. 4-qubit state (16 complex) lives in registers.
// Pre-CNOT circuit collapsed to tensor product of per-wire 2-vectors;
// CNOTs are compile-time index swaps; final Rx layer folded into the
// Z-measurement via Rx' Z Rx = cos(t) Z + sin(t) Y.
// Dtypes: inputs fp32 [n,4], theta fp32 [16], out fp32 [n,4,1].
// Encoder trig uses native v_sin_f32/v_cos_f32 (__sinf/__cosf): HW abs err
// ~1e-5 << 8.28e-3 threshold; precise __sincosf kept for shared theta consts.

__global__ __launch_bounds__(256) void qsim_kernel(
        const float* __restrict__ x,      // [n,4] float32
        const float* __restrict__ theta,  // [16]  float32
        float* __restrict__ out,          // [n,4] float32
        int n) {
    // ---- per-block: compose trainable constants into LDS (lanes 0..3) ----
    __shared__ __align__(16) float cst[40];
    int tid = threadIdx.x;
    if (tid < 4) {
        int q = tid;
        float a = theta[3*q], bb = theta[3*q+1], c = theta[3*q+2];
        float sa, ca, sb, cb, sc, cc;
        __sincosf(0.5f*a,  &sa, &ca);
        __sincosf(0.5f*bb, &sb, &cb);
        __sincosf(0.5f*c,  &sc, &cc);
        // M = Ry(bb) * Rx(a)
        float m00r =  cb*ca, m00i =  sb*sa;
        float m01r = -sb*ca, m01i = -cb*sa;
        float m10r =  sb*ca, m10i = -cb*sa;
        float m11r =  cb*ca, m11i = -sb*sa;
        // T = Rz(c) * M : row0 *= (cc - i sc), row1 *= (cc + i sc)
        float* T = cst + 8*q;
        T[0] = cc*m00r + sc*m00i;  T[1] = cc*m00i - sc*m00r;
        T[2] = cc*m01r + sc*m01i;  T[3] = cc*m01i - sc*m01r;
        T[4] = cc*m10r - sc*m10i;  T[5] = cc*m10i + sc*m10r;
        T[6] = cc*m11r - sc*m11i;  T[7] = cc*m11i + sc*m11r;
        // final rx(theta[12+q]) folded into measurement: cos(t), 2*sin(t)
        float sfq, cfq;
        __sincosf(theta[12+q], &sfq, &cfq);
        cst[32+q] = cfq;
        cst[36+q] = 2.0f*sfq;
    }
    __syncthreads();

    int b = blockIdx.x * 256 + tid;
    if (b >= n) return;

    float4 xv = ((const float4*)x)[b];

    // broadcast constants from LDS
    float T[32];
    #pragma unroll
    for (int i = 0; i < 8; ++i) ((float4*)T)[i] = ((const float4*)cst)[i];
    float4 cf  = ((const float4*)cst)[8];
    float4 sf2 = ((const float4*)cst)[9];

    // native HW trig: v_sin_f32 / v_cos_f32
    float s0 = __sinf(0.5f*xv.x), c0 = __cosf(0.5f*xv.x);
    float s1 = __sinf(0.5f*xv.y), c1 = __cosf(0.5f*xv.y);
    float s2 = __sinf(0.5f*xv.z), c2 = __cosf(0.5f*xv.z);
    float s3 = __sinf(0.5f*xv.w), c3 = __cosf(0.5f*xv.w);

    // v_q = T_q * (Enc_q |0>), a = component |0>, b = component |1>
    float var[4], vai[4], vbr[4], vbi[4];
    {   // wire0: rx(x0): e = (c0, -i s0)
        const float* t = T + 0;
        var[0] = t[0]*c0 + t[3]*s0;  vai[0] = t[1]*c0 - t[2]*s0;
        vbr[0] = t[4]*c0 + t[7]*s0;  vbi[0] = t[5]*c0 - t[6]*s0;
    }
    {   // wire1: ry(x1): e = (c1, s1)
        const float* t = T + 8;
        var[1] = t[0]*c1 + t[2]*s1;  vai[1] = t[1]*c1 + t[3]*s1;
        vbr[1] = t[4]*c1 + t[6]*s1;  vbi[1] = t[5]*c1 + t[7]*s1;
    }
    {   // wire2: rz(x2): e = (c2 - i s2, 0) -> v = (c2 - i s2) * T[:,0]
        const float* t = T + 16;
        var[2] = t[0]*c2 + t[1]*s2;  vai[2] = t[1]*c2 - t[0]*s2;
        vbr[2] = t[4]*c2 + t[5]*s2;  vbi[2] = t[5]*c2 - t[4]*s2;
    }
    {   // wire3: rx(x3)
        const float* t = T + 24;
        var[3] = t[0]*c3 + t[3]*s3;  vai[3] = t[1]*c3 - t[2]*s3;
        vbr[3] = t[4]*c3 + t[7]*s3;  vbi[3] = t[5]*c3 - t[6]*s3;
    }

    // tensor products: index i = 8*b0 + 4*b1 + 2*b2 + b3 (wire0 = MSB)
    float u01r[4], u01i[4], u23r[4], u23i[4];
    #pragma unroll
    for (int i0 = 0; i0 < 2; ++i0) {
        float ar = i0 ? vbr[0] : var[0], ai = i0 ? vbi[0] : vai[0];
        #pragma unroll
        for (int i1 = 0; i1 < 2; ++i1) {
            float br = i1 ? vbr[1] : var[1], bi = i1 ? vbi[1] : vai[1];
            u01r[2*i0+i1] = ar*br - ai*bi;
            u01i[2*i0+i1] = ar*bi + ai*br;
        }
    }
    #pragma unroll
    for (int i2 = 0; i2 < 2; ++i2) {
        float ar = i2 ? vbr[2] : var[2], ai = i2 ? vbi[2] : vai[2];
        #pragma unroll
        for (int i3 = 0; i3 < 2; ++i3) {
            float br = i3 ? vbr[3] : var[3], bi = i3 ? vbi[3] : vai[3];
            u23r[2*i2+i3] = ar*br - ai*bi;
            u23i[2*i2+i3] = ar*bi + ai*br;
        }
    }
    float pr[16], pi[16];
    #pragma unroll
    for (int h = 0; h < 4; ++h)
        #pragma unroll
        for (int l = 0; l < 4; ++l) {
            pr[4*h+l] = u01r[h]*u23r[l] - u01i[h]*u23i[l];
            pi[4*h+l] = u01r[h]*u23i[l] + u01i[h]*u23r[l];
        }

    // CNOTs (0,1),(1,2),(2,3),(3,0): constant-index swaps (register renames)
    #define SWP(A,Bq) { float t_; t_=pr[A]; pr[A]=pr[Bq]; pr[Bq]=t_; \
                        t_=pi[A]; pi[A]=pi[Bq]; pi[Bq]=t_; }
    SWP(8,12)  SWP(9,13)  SWP(10,14) SWP(11,15)   // CNOT(0,1): c=bit8, t=bit4
    SWP(4,6)   SWP(5,7)   SWP(12,14) SWP(13,15)   // CNOT(1,2): c=bit4, t=bit2
    SWP(2,3)   SWP(6,7)   SWP(10,11) SWP(14,15)   // CNOT(2,3): c=bit2, t=bit1
    SWP(1,9)   SWP(3,11)  SWP(5,13)  SWP(7,15)    // CNOT(3,0): c=bit1, t=bit8
    #undef SWP

    // probabilities
    float d[16];
    #pragma unroll
    for (int i = 0; i < 16; ++i) d[i] = pr[i]*pr[i] + pi[i]*pi[i];

    // <Z_w> via shared tree
    float s1a[8], d1[8];
    #pragma unroll
    for (int k = 0; k < 8; ++k) { s1a[k] = d[2*k]+d[2*k+1]; d1[k] = d[2*k]-d[2*k+1]; }
    float z3 = ((d1[0]+d1[1])+(d1[2]+d1[3])) + ((d1[4]+d1[5])+(d1[6]+d1[7]));
    float s2a[4], d2[4];
    #pragma unroll
    for (int k = 0; k < 4; ++k) { s2a[k] = s1a[2*k]+s1a[2*k+1]; d2[k] = s1a[2*k]-s1a[2*k+1]; }
    float z2 = (d2[0]+d2[1]) + (d2[2]+d2[3]);
    float s3a[2], d3[2];
    #pragma unroll
    for (int k = 0; k < 2; ++k) { s3a[k] = s2a[2*k]+s2a[2*k+1]; d3[k] = s2a[2*k]-s2a[2*k+1]; }
    float z1 = d3[0] + d3[1];
    float z0 = s3a[0] - s3a[1];

    // <Y_w> = 2 * sum_pairs Im(conj(a0)*a1); factor 2 folded into sf2
    float y[4];
    #pragma unroll
    for (int w = 0; w < 4; ++w) {
        int m = 8 >> w;
        float acc = 0.f;
        #pragma unroll
        for (int i = 0; i < 16; ++i)
            if (!(i & m)) acc += pr[i]*pi[i+m] - pi[i]*pr[i+m];
        y[w] = acc;
    }

    float4 o;
    o.x = cf.x*z0 + sf2.x*y[0];
    o.y = cf.y*z1 + sf2.y*y[1];
    o.z = cf.z*z2 + sf2.z*y[2];
    o.w = cf.w*z3 + sf2.w*y[3];
    ((float4*)out)[b] = o;
}

extern "C" void kernel_launch(void* const* d_in, const int* in_sizes, int n_in,
                              void* d_out, int out_size, void* d_ws, size_t ws_size,
                              hipStream_t stream) {
    const float* inputs = (const float*)d_in[0];
    const float* theta  = (const float*)d_in[1];
    float* out = (float*)d_out;
    int n = in_sizes[0] / 4;
    int blocks = (n + 255) / 256;
    qsim_kernel<<<blocks, 256, 0, stream>>>(inputs, theta, out, n);
}